// Round 3
// baseline (342.071 us; speedup 1.0000x reference)
//
#include <hip/hip_runtime.h>

// B=2, L=4096, D=512, H=8, DK=64. out = Attn(x W_qkv^T) W_o^T, fp32 io.
// R3: barrier-free attention (K/V frags direct from L1/L2, LDS only for the
// per-wave P round-trip), S^T trick for b64 P-writes, denom via ones-MFMA,
// v-transpose moved to a dedicated LDS-tile kernel, fused casts.

#define Bq 2
#define Lq 4096
#define Dq 512
#define Hq 8
#define DKq 64
#define PST 72  // P row stride (elems): 144B = 16B-aligned, spreads banks

using short8  = __attribute__((ext_vector_type(8))) short;
using ushort8 = __attribute__((ext_vector_type(8))) unsigned short;
using float4v = __attribute__((ext_vector_type(4))) float;
typedef unsigned short u16;
typedef unsigned int   u32;

__device__ __forceinline__ u16 f2bf(float f) {
    u32 u = __float_as_uint(f);
    u += 0x7fffu + ((u >> 16) & 1u);   // RNE
    return (u16)(u >> 16);
}

__device__ __forceinline__ float4v mfma16(short8 a, short8 b, float4v c) {
    return __builtin_amdgcn_mfma_f32_16x16x32_bf16(a, b, c, 0, 0, 0);
}

// async 16B/lane global->LDS
__device__ __forceinline__ void gload_lds16(const u16* g, u16* l) {
    __builtin_amdgcn_global_load_lds(
        (const __attribute__((address_space(1))) unsigned int*)g,
        (__attribute__((address_space(3))) unsigned int*)l,
        16, 0, 0);
}

// ---------------- fused cast fp32 -> bf16 for all three inputs ----------------
__global__ __launch_bounds__(256) void castall(const float* __restrict__ x,
                                               const float* __restrict__ wq,
                                               const float* __restrict__ wo,
                                               u16* __restrict__ xb,
                                               u16* __restrict__ wqb,
                                               u16* __restrict__ wob) {
    int g = blockIdx.x;
    const float* s; u16* d; int base;
    if (g < 4096)      { s = x;  d = xb;  base = g * 1024; }
    else if (g < 4864) { s = wq; d = wqb; base = (g - 4096) * 1024; }
    else               { s = wo; d = wob; base = (g - 4864) * 1024; }
    int i = base + threadIdx.x * 4;
    float4 f = *(const float4*)&s[i];
    ushort4 o;
    o.x = f2bf(f.x); o.y = f2bf(f.y); o.z = f2bf(f.z); o.w = f2bf(f.w);
    *(ushort4*)&d[i] = o;
}

// ---------------- QKV projection: C[8192,1536] = X[8192,512] @ W[1536,512]^T ----
// q prescaled 1/8; q,k,v all stored [B,H,L,DK] (v transposed later).
__global__ __launch_bounds__(256) void qkv_gemm(const u16* __restrict__ A,
                                                const u16* __restrict__ Bw,
                                                u16* __restrict__ qb,
                                                u16* __restrict__ kb,
                                                u16* __restrict__ vt) {
    __shared__ __align__(16) u16 As[128 * 64];
    __shared__ __align__(16) u16 Bs[128 * 64];
    const int m0 = blockIdx.x * 128, n0 = blockIdx.y * 128;
    const int tid = threadIdx.x, w = tid >> 6, lane = tid & 63;
    const int l15 = lane & 15, quad = lane >> 4;
    const int wy = w & 1, wx = w >> 1;
    const int r8 = lane >> 3, c8 = lane & 7, csw = c8 ^ r8;
    const int sw = l15 & 7;

    float4v acc[4][4];
    float4v zero = {0.f, 0.f, 0.f, 0.f};
#pragma unroll
    for (int mi = 0; mi < 4; mi++)
#pragma unroll
        for (int ni = 0; ni < 4; ni++) acc[mi][ni] = zero;

    for (int k0 = 0; k0 < 512; k0 += 64) {
#pragma unroll
        for (int i = 0; i < 4; i++) {
            int row = w * 32 + i * 8;
            gload_lds16(&A[(size_t)(m0 + row + r8) * 512 + k0 + csw * 8], &As[row * 64]);
            gload_lds16(&Bw[(size_t)(n0 + row + r8) * 512 + k0 + csw * 8], &Bs[row * 64]);
        }
        __syncthreads();
        short8 af0[4], af1[4], bf0[4], bf1[4];
#pragma unroll
        for (int t = 0; t < 4; t++) {
            int rowA = wy * 64 + t * 16 + l15;
            af0[t] = *(const short8*)&As[rowA * 64 + ((quad ^ sw) * 8)];
            af1[t] = *(const short8*)&As[rowA * 64 + (((quad + 4) ^ sw) * 8)];
            int rowB = wx * 64 + t * 16 + l15;
            bf0[t] = *(const short8*)&Bs[rowB * 64 + ((quad ^ sw) * 8)];
            bf1[t] = *(const short8*)&Bs[rowB * 64 + (((quad + 4) ^ sw) * 8)];
        }
#pragma unroll
        for (int mi = 0; mi < 4; mi++)
#pragma unroll
            for (int ni = 0; ni < 4; ni++) {
                acc[mi][ni] = mfma16(af0[mi], bf0[ni], acc[mi][ni]);
                acc[mi][ni] = mfma16(af1[mi], bf1[ni], acc[mi][ni]);
            }
        __syncthreads();
    }

#pragma unroll
    for (int mi = 0; mi < 4; mi++)
#pragma unroll
        for (int ni = 0; ni < 4; ni++)
#pragma unroll
            for (int r = 0; r < 4; r++) {
                int i = m0 + wy * 64 + mi * 16 + quad * 4 + r;
                int j = n0 + wx * 64 + ni * 16 + l15;
                float v = acc[mi][ni][r];
                int sel = j >> 9, rem = j & 511, h = rem >> 6, dk = rem & 63;
                int b = i >> 12, l = i & 4095;
                u16* tgt = (sel == 0) ? qb : ((sel == 1) ? kb : vt);
                float sc = (sel == 0) ? 0.125f : 1.0f;
                tgt[((size_t)(b * Hq + h) * Lq + l) * DKq + dk] = f2bf(v * sc);
            }
}

// ---------------- V transpose: [bh][L][DK] -> [bh][DK][L] -------------------
__global__ __launch_bounds__(256) void vtrans(const u16* __restrict__ vt,
                                              u16* __restrict__ vb) {
    __shared__ __align__(16) u16 T[64][PST];
    const int l0 = blockIdx.x * 64, bh = blockIdx.y;
    const u16* src = vt + (size_t)bh * Lq * DKq;
    u16* dst = vb + (size_t)bh * DKq * Lq;
    const int t = threadIdx.x;
    const int r = t >> 2, c = (t & 3) * 16;
    *(ushort8*)&T[r][c]     = *(const ushort8*)&src[(size_t)(l0 + r) * DKq + c];
    *(ushort8*)&T[r][c + 8] = *(const ushort8*)&src[(size_t)(l0 + r) * DKq + c + 8];
    __syncthreads();
    ushort8 o0, o1;
#pragma unroll
    for (int i = 0; i < 8; i++) { o0[i] = T[c + i][r]; o1[i] = T[c + 8 + i][r]; }
    *(ushort8*)&dst[(size_t)r * Lq + l0 + c]     = o0;
    *(ushort8*)&dst[(size_t)r * Lq + l0 + c + 8] = o1;
}

// ---------------- attention: barrier-free, block = (bh, 128 q-rows) ---------
__global__ __launch_bounds__(256, 2) void attn_kern(const u16* __restrict__ qb,
                                                    const u16* __restrict__ kb,
                                                    const u16* __restrict__ vb,
                                                    u16* __restrict__ ctx) {
    __shared__ __align__(16) u16 Ps[4 * 32 * PST];
    const int g = blockIdx.x;
    // XCD swizzle: xcd = g%8 serves bh {2*xcd, 2*xcd+1} -> K/V L2-resident
    const int bh = (g & 7) * 2 + ((g >> 3) & 1);
    const int q0 = (g >> 4) * 128;
    const int tid = threadIdx.x;
    const int w = tid >> 6, lane = tid & 63, l15 = lane & 15, quad = lane >> 4;

    const u16* qbase = qb + (size_t)bh * Lq * DKq;
    const u16* kbase = kb + (size_t)bh * Lq * DKq;
    const u16* vtb   = vb + (size_t)bh * DKq * Lq;

    // Q fragments (B-operand for S^T), 2 rowsets; q pre-scaled 1/8.
    short8 aq0[2], aq1[2];
#pragma unroll
    for (int s = 0; s < 2; s++) {
        int qrow = q0 + w * 32 + s * 16 + l15;
        aq0[s] = *(const short8*)&qbase[(size_t)qrow * DKq + quad * 8];
        aq1[s] = *(const short8*)&qbase[(size_t)qrow * DKq + 32 + quad * 8];
    }

    short8 ones;
#pragma unroll
    for (int j = 0; j < 8; j++) ones[j] = (short)0x3F80;  // bf16 1.0

    float4v zero = {0.f, 0.f, 0.f, 0.f};
    float4v oacc[2][4], den[2];
#pragma unroll
    for (int s = 0; s < 2; s++) {
        den[s] = zero;
#pragma unroll
        for (int n = 0; n < 4; n++) oacc[s][n] = zero;
    }

    u16* Pw = Ps + w * 32 * PST;  // per-wave private P region

    for (int j0 = 0; j0 < Lq; j0 += 64) {
        // K/V fragments straight from global (L1/L2-resident tiles)
        short8 kf0[4], kf1[4], vf0[4], vf1[4];
#pragma unroll
        for (int n = 0; n < 4; n++) {
            const u16* kr = &kbase[(size_t)(j0 + n * 16 + l15) * DKq + quad * 8];
            kf0[n] = *(const short8*)kr;
            kf1[n] = *(const short8*)(kr + 32);
            const u16* vr = &vtb[(size_t)(n * 16 + l15) * Lq + j0 + quad * 8];
            vf0[n] = *(const short8*)vr;
            vf1[n] = *(const short8*)(vr + 32);
        }

        // S^T = K Q^T (so P lands key-contiguous per lane), P = exp -> LDS b64
#pragma unroll
        for (int s = 0; s < 2; s++) {
#pragma unroll
            for (int nk = 0; nk < 4; nk++) {
                float4v sv = zero;
                sv = mfma16(kf0[nk], aq0[s], sv);
                sv = mfma16(kf1[nk], aq1[s], sv);
                u32 u0 = __float_as_uint(__expf(sv[0])) + 0x8000u;
                u32 u1 = __float_as_uint(__expf(sv[1])) + 0x8000u;
                u32 u2 = __float_as_uint(__expf(sv[2])) + 0x8000u;
                u32 u3 = __float_as_uint(__expf(sv[3])) + 0x8000u;
                uint2 pv;
                pv.x = __builtin_amdgcn_perm(u1, u0, 0x07060302u);
                pv.y = __builtin_amdgcn_perm(u3, u2, 0x07060302u);
                *(uint2*)&Pw[(s * 16 + l15) * PST + nk * 16 + quad * 4] = pv;
            }
        }

        // O += P V ; denom += P . 1   (same C-layout as O — no shuffles)
#pragma unroll
        for (int s = 0; s < 2; s++) {
            short8 ap0 = *(const short8*)&Pw[(s * 16 + l15) * PST + quad * 8];
            short8 ap1 = *(const short8*)&Pw[(s * 16 + l15) * PST + 32 + quad * 8];
            den[s] = mfma16(ap0, ones, den[s]);
            den[s] = mfma16(ap1, ones, den[s]);
#pragma unroll
            for (int n = 0; n < 4; n++) {
                oacc[s][n] = mfma16(ap0, vf0[n], oacc[s][n]);
                oacc[s][n] = mfma16(ap1, vf1[n], oacc[s][n]);
            }
        }
    }

    const int b = bh >> 3, h = bh & 7;
#pragma unroll
    for (int s = 0; s < 2; s++)
#pragma unroll
        for (int r = 0; r < 4; r++) {
            float rd = __builtin_amdgcn_rcpf(den[s][r]);
            int row = q0 + w * 32 + s * 16 + quad * 4 + r;
#pragma unroll
            for (int n = 0; n < 4; n++) {
                float o = oacc[s][n][r] * rd;
                ctx[((size_t)(b * Lq + row)) * Dq + h * DKq + n * 16 + l15] = f2bf(o);
            }
        }
}

// ---------------- output projection: out[8192,512] = ctx @ Wo^T (fp32 out) ----
__global__ __launch_bounds__(256) void out_gemm(const u16* __restrict__ A,
                                                const u16* __restrict__ Bw,
                                                float* __restrict__ out) {
    __shared__ __align__(16) u16 As[128 * 64];
    __shared__ __align__(16) u16 Bs[128 * 64];
    const int m0 = blockIdx.x * 128, n0 = blockIdx.y * 128;
    const int tid = threadIdx.x, w = tid >> 6, lane = tid & 63;
    const int l15 = lane & 15, quad = lane >> 4;
    const int wy = w & 1, wx = w >> 1;
    const int r8 = lane >> 3, c8 = lane & 7, csw = c8 ^ r8;
    const int sw = l15 & 7;

    float4v acc[4][4];
    float4v zero = {0.f, 0.f, 0.f, 0.f};
#pragma unroll
    for (int mi = 0; mi < 4; mi++)
#pragma unroll
        for (int ni = 0; ni < 4; ni++) acc[mi][ni] = zero;

    for (int k0 = 0; k0 < 512; k0 += 64) {
#pragma unroll
        for (int i = 0; i < 4; i++) {
            int row = w * 32 + i * 8;
            gload_lds16(&A[(size_t)(m0 + row + r8) * 512 + k0 + csw * 8], &As[row * 64]);
            gload_lds16(&Bw[(size_t)(n0 + row + r8) * 512 + k0 + csw * 8], &Bs[row * 64]);
        }
        __syncthreads();
        short8 af0[4], af1[4], bf0[4], bf1[4];
#pragma unroll
        for (int t = 0; t < 4; t++) {
            int rowA = wy * 64 + t * 16 + l15;
            af0[t] = *(const short8*)&As[rowA * 64 + ((quad ^ sw) * 8)];
            af1[t] = *(const short8*)&As[rowA * 64 + (((quad + 4) ^ sw) * 8)];
            int rowB = wx * 64 + t * 16 + l15;
            bf0[t] = *(const short8*)&Bs[rowB * 64 + ((quad ^ sw) * 8)];
            bf1[t] = *(const short8*)&Bs[rowB * 64 + (((quad + 4) ^ sw) * 8)];
        }
#pragma unroll
        for (int mi = 0; mi < 4; mi++)
#pragma unroll
            for (int ni = 0; ni < 4; ni++) {
                acc[mi][ni] = mfma16(af0[mi], bf0[ni], acc[mi][ni]);
                acc[mi][ni] = mfma16(af1[mi], bf1[ni], acc[mi][ni]);
            }
        __syncthreads();
    }

#pragma unroll
    for (int mi = 0; mi < 4; mi++)
#pragma unroll
        for (int ni = 0; ni < 4; ni++)
#pragma unroll
            for (int r = 0; r < 4; r++) {
                int i = m0 + wy * 64 + mi * 16 + quad * 4 + r;
                int j = n0 + wx * 64 + ni * 16 + l15;
                out[(size_t)i * 512 + j] = acc[mi][ni][r];
            }
}

extern "C" void kernel_launch(void* const* d_in, const int* in_sizes, int n_in,
                              void* d_out, int out_size, void* d_ws, size_t ws_size,
                              hipStream_t stream) {
    const float* x     = (const float*)d_in[0];   // [2,4096,512]
    const float* w_qkv = (const float*)d_in[1];   // [1536,512]
    const float* w_o   = (const float*)d_in[2];   // [512,512]
    float* out = (float*)d_out;

    const size_t N_X   = (size_t)Bq * Lq * Dq;        // 4194304
    const size_t N_WQ  = (size_t)3 * Dq * Dq;         // 786432
    const size_t N_WO  = (size_t)Dq * Dq;             // 262144
    const size_t N_QKV = (size_t)Bq * Hq * Lq * DKq;  // 4194304 each

    u16* xb  = (u16*)d_ws;
    u16* wqb = xb + N_X;
    u16* wob = wqb + N_WQ;
    u16* qb  = wob + N_WO;
    u16* kb  = qb + N_QKV;
    u16* vt  = kb + N_QKV;
    u16* ctx = vt + N_QKV;
    u16* vb  = xb;  // reuse xb (dead after qkv_gemm) for V^T — keeps ws at 44 MB

    castall<<<dim3(5120), 256, 0, stream>>>(x, w_qkv, w_o, xb, wqb, wob);
    qkv_gemm<<<dim3(64, 12), 256, 0, stream>>>(xb, wqb, qb, kb, vt);
    vtrans<<<dim3(64, 16), 256, 0, stream>>>(vt, vb);
    attn_kern<<<dim3(512), 256, 0, stream>>>(qb, kb, vb, ctx);
    out_gemm<<<dim3(64, 4), 256, 0, stream>>>(ctx, wob, out);
}

// Round 4
// 198.935 us; speedup vs baseline: 1.7195x; 1.7195x over previous
//
#include <hip/hip_runtime.h>

// B=2, L=4096, D=512, H=8, DK=64. out = Attn(x W_qkv^T) W_o^T, fp32 io.
// R4: back to LDS-staged attention (R2 base) + split-K(2) for 16 waves/CU
// occupancy + R3's verified S^T/perm/ones-denom tricks + V^T direct store.

#define Bq 2
#define Lq 4096
#define Dq 512
#define Hq 8
#define DKq 64
#define PST 72  // P row stride (elems): 144B -> 2-way bank aliasing only (free)

using short8  = __attribute__((ext_vector_type(8))) short;
using float4v = __attribute__((ext_vector_type(4))) float;
using half4   = __attribute__((ext_vector_type(4))) _Float16;
typedef unsigned short u16;
typedef unsigned int   u32;

__device__ __forceinline__ u16 f2bf(float f) {
    u32 u = __float_as_uint(f);
    u += 0x7fffu + ((u >> 16) & 1u);   // RNE
    return (u16)(u >> 16);
}

__device__ __forceinline__ float4v mfma16(short8 a, short8 b, float4v c) {
    return __builtin_amdgcn_mfma_f32_16x16x32_bf16(a, b, c, 0, 0, 0);
}

__device__ __forceinline__ void gload_lds16(const u16* g, u16* l) {
    __builtin_amdgcn_global_load_lds(
        (const __attribute__((address_space(1))) unsigned int*)g,
        (__attribute__((address_space(3))) unsigned int*)l,
        16, 0, 0);
}

// ---------------- fused cast fp32 -> bf16 ----------------
__global__ __launch_bounds__(256) void castall(const float* __restrict__ x,
                                               const float* __restrict__ wq,
                                               const float* __restrict__ wo,
                                               u16* __restrict__ xb,
                                               u16* __restrict__ wqb,
                                               u16* __restrict__ wob) {
    int g = blockIdx.x;
    const float* s; u16* d; int base;
    if (g < 4096)      { s = x;  d = xb;  base = g * 1024; }
    else if (g < 4864) { s = wq; d = wqb; base = (g - 4096) * 1024; }
    else               { s = wo; d = wob; base = (g - 4864) * 1024; }
    int i = base + threadIdx.x * 4;
    float4 f = *(const float4*)&s[i];
    ushort4 o;
    o.x = f2bf(f.x); o.y = f2bf(f.y); o.z = f2bf(f.z); o.w = f2bf(f.w);
    *(ushort4*)&d[i] = o;
}

// ---------------- QKV proj: C[8192,1536] = X @ W^T; scatter q(x1/8), k, V^T ----
__global__ __launch_bounds__(256) void qkv_gemm(const u16* __restrict__ A,
                                                const u16* __restrict__ Bw,
                                                u16* __restrict__ qb,
                                                u16* __restrict__ kb,
                                                u16* __restrict__ vt) {
    __shared__ __align__(16) u16 As[128 * 64];
    __shared__ __align__(16) u16 Bs[128 * 64];
    const int m0 = blockIdx.x * 128, n0 = blockIdx.y * 128;
    const int tid = threadIdx.x, w = tid >> 6, lane = tid & 63;
    const int l15 = lane & 15, quad = lane >> 4;
    const int wy = w & 1, wx = w >> 1;
    const int r8 = lane >> 3, c8 = lane & 7, csw = c8 ^ r8;
    const int sw = l15 & 7;

    float4v acc[4][4];
    float4v zero = {0.f, 0.f, 0.f, 0.f};
#pragma unroll
    for (int mi = 0; mi < 4; mi++)
#pragma unroll
        for (int ni = 0; ni < 4; ni++) acc[mi][ni] = zero;

    for (int k0 = 0; k0 < 512; k0 += 64) {
#pragma unroll
        for (int i = 0; i < 4; i++) {
            int row = w * 32 + i * 8;
            gload_lds16(&A[(size_t)(m0 + row + r8) * 512 + k0 + csw * 8], &As[row * 64]);
            gload_lds16(&Bw[(size_t)(n0 + row + r8) * 512 + k0 + csw * 8], &Bs[row * 64]);
        }
        __syncthreads();
        short8 af0[4], af1[4], bf0[4], bf1[4];
#pragma unroll
        for (int t = 0; t < 4; t++) {
            int rowA = wy * 64 + t * 16 + l15;
            af0[t] = *(const short8*)&As[rowA * 64 + ((quad ^ sw) * 8)];
            af1[t] = *(const short8*)&As[rowA * 64 + (((quad + 4) ^ sw) * 8)];
            int rowB = wx * 64 + t * 16 + l15;
            bf0[t] = *(const short8*)&Bs[rowB * 64 + ((quad ^ sw) * 8)];
            bf1[t] = *(const short8*)&Bs[rowB * 64 + (((quad + 4) ^ sw) * 8)];
        }
#pragma unroll
        for (int mi = 0; mi < 4; mi++)
#pragma unroll
            for (int ni = 0; ni < 4; ni++) {
                acc[mi][ni] = mfma16(af0[mi], bf0[ni], acc[mi][ni]);
                acc[mi][ni] = mfma16(af1[mi], bf1[ni], acc[mi][ni]);
            }
        __syncthreads();
    }

#pragma unroll
    for (int mi = 0; mi < 4; mi++)
#pragma unroll
        for (int ni = 0; ni < 4; ni++) {
            int i0 = m0 + wy * 64 + mi * 16 + quad * 4;
            int j  = n0 + wx * 64 + ni * 16 + l15;
            int sel = j >> 9, rem = j & 511, h = rem >> 6, dk = rem & 63;
            int b = i0 >> 12, l = i0 & 4095;
            if (sel == 2) {
                // V^T [bh][dk][l]: 4 consecutive l per lane -> one b64 store
                ushort4 v4;
                v4.x = f2bf(acc[mi][ni][0]); v4.y = f2bf(acc[mi][ni][1]);
                v4.z = f2bf(acc[mi][ni][2]); v4.w = f2bf(acc[mi][ni][3]);
                *(ushort4*)&vt[((size_t)(b * Hq + h) * DKq + dk) * Lq + l] = v4;
            } else {
                u16* tgt = (sel == 0) ? qb : kb;
                float sc = (sel == 0) ? 0.125f : 1.0f;
#pragma unroll
                for (int r = 0; r < 4; r++)
                    tgt[((size_t)(b * Hq + h) * Lq + (l + r)) * DKq + dk] = f2bf(acc[mi][ni][r] * sc);
            }
        }
}

// ---------------- attention: split-K(2), LDS-staged, 128 q-rows/block --------
__global__ __launch_bounds__(256, 4) void attn_kern(const u16* __restrict__ qb,
                                                    const u16* __restrict__ kb,
                                                    const u16* __restrict__ vt,
                                                    _Float16* __restrict__ op0,
                                                    _Float16* __restrict__ op1,
                                                    float* __restrict__ denp) {
    __shared__ __align__(16) u16 Ks[64 * 64];
    __shared__ __align__(16) u16 Vs[64 * 64];
    __shared__ __align__(16) u16 Ps[4 * 32 * PST];
    const int g = blockIdx.x;          // 1024
    const int xcd = g & 7, idx = g >> 3;
    const int bh = xcd * 2 + (idx & 1);
    const int rest = idx >> 1;         // 0..63
    const int split = rest & 1;
    const int q0 = (rest >> 1) * 128;  // 32 q-tiles
    const int tid = threadIdx.x;
    const int w = tid >> 6, lane = tid & 63, l15 = lane & 15, quad = lane >> 4;
    const int r8 = lane >> 3, c8 = lane & 7, csw = c8 ^ r8;
    const int sw = l15 & 7;

    const u16* qbase = qb + (size_t)bh * Lq * DKq;
    const u16* kbase = kb + (size_t)bh * Lq * DKq;
    const u16* vbase = vt + (size_t)bh * DKq * Lq;

    short8 aq0[2], aq1[2];
#pragma unroll
    for (int s = 0; s < 2; s++) {
        int qrow = q0 + w * 32 + s * 16 + l15;
        aq0[s] = *(const short8*)&qbase[(size_t)qrow * DKq + quad * 8];
        aq1[s] = *(const short8*)&qbase[(size_t)qrow * DKq + 32 + quad * 8];
    }

    short8 ones;
#pragma unroll
    for (int j = 0; j < 8; j++) ones[j] = (short)0x3F80;  // bf16 1.0

    float4v zero = {0.f, 0.f, 0.f, 0.f};
    float4v oacc[2][4], den[2];
#pragma unroll
    for (int s = 0; s < 2; s++) {
        den[s] = zero;
#pragma unroll
        for (int n = 0; n < 4; n++) oacc[s][n] = zero;
    }

    u16* Pw = Ps + w * 32 * PST;
    const int j0base = split * 2048;

    for (int jt = 0; jt < 32; jt++) {
        int j0 = j0base + jt * 64;
        if (w < 2) {
#pragma unroll
            for (int i = 0; i < 4; i++) {
                int base = w * 32 + i * 8;
                gload_lds16(&kbase[(size_t)(j0 + base + r8) * DKq + csw * 8], &Ks[base * 64]);
            }
        } else {
#pragma unroll
            for (int i = 0; i < 4; i++) {
                int base = (w - 2) * 32 + i * 8;
                gload_lds16(&vbase[(size_t)(base + r8) * Lq + j0 + csw * 8], &Vs[base * 64]);
            }
        }
        __syncthreads();

        short8 kf0[4], kf1[4], vf0[4], vf1[4];
#pragma unroll
        for (int n = 0; n < 4; n++) {
            int row = n * 16 + l15;
            kf0[n] = *(const short8*)&Ks[row * 64 + ((quad ^ sw) * 8)];
            kf1[n] = *(const short8*)&Ks[row * 64 + (((quad + 4) ^ sw) * 8)];
            vf0[n] = *(const short8*)&Vs[row * 64 + ((quad ^ sw) * 8)];
            vf1[n] = *(const short8*)&Vs[row * 64 + (((quad + 4) ^ sw) * 8)];
        }

        // S^T = K Q^T -> P = exp -> LDS (b64 packed writes)
#pragma unroll
        for (int s = 0; s < 2; s++) {
#pragma unroll
            for (int nk = 0; nk < 4; nk++) {
                float4v sv = zero;
                sv = mfma16(kf0[nk], aq0[s], sv);
                sv = mfma16(kf1[nk], aq1[s], sv);
                u32 u0 = __float_as_uint(__expf(sv[0])) + 0x8000u;
                u32 u1 = __float_as_uint(__expf(sv[1])) + 0x8000u;
                u32 u2 = __float_as_uint(__expf(sv[2])) + 0x8000u;
                u32 u3 = __float_as_uint(__expf(sv[3])) + 0x8000u;
                uint2 pv;
                pv.x = __builtin_amdgcn_perm(u1, u0, 0x07060302u);
                pv.y = __builtin_amdgcn_perm(u3, u2, 0x07060302u);
                *(uint2*)&Pw[(s * 16 + l15) * PST + nk * 16 + quad * 4] = pv;
            }
        }

        // O += P V ; den += P . 1
#pragma unroll
        for (int s = 0; s < 2; s++) {
            short8 ap0 = *(const short8*)&Pw[(s * 16 + l15) * PST + quad * 8];
            short8 ap1 = *(const short8*)&Pw[(s * 16 + l15) * PST + 32 + quad * 8];
            den[s] = mfma16(ap0, ones, den[s]);
            den[s] = mfma16(ap1, ones, den[s]);
#pragma unroll
            for (int n = 0; n < 4; n++) {
                oacc[s][n] = mfma16(ap0, vf0[n], oacc[s][n]);
                oacc[s][n] = mfma16(ap1, vf1[n], oacc[s][n]);
            }
        }
        __syncthreads();
    }

    // epilogue: write normalized partial O (fp16) + partial den (fp32)
    _Float16* op = split ? op1 : op0;
#pragma unroll
    for (int s = 0; s < 2; s++)
#pragma unroll
        for (int r = 0; r < 4; r++) {
            float dv = den[s][r];
            float rd = __builtin_amdgcn_rcpf(dv);
            int row = q0 + w * 32 + s * 16 + quad * 4 + r;
            if (l15 == 0) denp[(size_t)(split * 16 + bh) * Lq + row] = dv;
#pragma unroll
            for (int n = 0; n < 4; n++)
                op[((size_t)bh * Lq + row) * DKq + n * 16 + l15] =
                    (_Float16)(oacc[s][n][r] * rd);
        }
}

// ---------------- combine: ctx = (o0*d0 + o1*d1)/(d0+d1), bf16 --------------
__global__ __launch_bounds__(256) void combine(const _Float16* __restrict__ op0,
                                               const _Float16* __restrict__ op1,
                                               const float* __restrict__ denp,
                                               u16* __restrict__ ctxq) {
    int t = blockIdx.x * 256 + threadIdx.x;  // 1,048,576
    int dk4 = t & 15, l = (t >> 4) & 4095, bh = t >> 16;
    size_t r0 = (size_t)bh * Lq + l;
    half4 h0 = *(const half4*)&op0[r0 * DKq + dk4 * 4];
    half4 h1 = *(const half4*)&op1[r0 * DKq + dk4 * 4];
    float d0 = denp[r0];
    float d1 = denp[(size_t)(16 + bh) * Lq + l];
    float rs = __builtin_amdgcn_rcpf(d0 + d1);
    int b = bh >> 3, h = bh & 7;
    ushort4 o;
    o.x = f2bf(((float)h0.x * d0 + (float)h1.x * d1) * rs);
    o.y = f2bf(((float)h0.y * d0 + (float)h1.y * d1) * rs);
    o.z = f2bf(((float)h0.z * d0 + (float)h1.z * d1) * rs);
    o.w = f2bf(((float)h0.w * d0 + (float)h1.w * d1) * rs);
    *(ushort4*)&ctxq[((size_t)(b * Lq + l)) * Dq + h * DKq + dk4 * 4] = o;
}

// ---------------- output projection: out[8192,512] = ctx @ Wo^T (fp32 out) ----
__global__ __launch_bounds__(256) void out_gemm(const u16* __restrict__ A,
                                                const u16* __restrict__ Bw,
                                                float* __restrict__ out) {
    __shared__ __align__(16) u16 As[128 * 64];
    __shared__ __align__(16) u16 Bs[128 * 64];
    const int m0 = blockIdx.x * 128, n0 = blockIdx.y * 128;
    const int tid = threadIdx.x, w = tid >> 6, lane = tid & 63;
    const int l15 = lane & 15, quad = lane >> 4;
    const int wy = w & 1, wx = w >> 1;
    const int r8 = lane >> 3, c8 = lane & 7, csw = c8 ^ r8;
    const int sw = l15 & 7;

    float4v acc[4][4];
    float4v zero = {0.f, 0.f, 0.f, 0.f};
#pragma unroll
    for (int mi = 0; mi < 4; mi++)
#pragma unroll
        for (int ni = 0; ni < 4; ni++) acc[mi][ni] = zero;

    for (int k0 = 0; k0 < 512; k0 += 64) {
#pragma unroll
        for (int i = 0; i < 4; i++) {
            int row = w * 32 + i * 8;
            gload_lds16(&A[(size_t)(m0 + row + r8) * 512 + k0 + csw * 8], &As[row * 64]);
            gload_lds16(&Bw[(size_t)(n0 + row + r8) * 512 + k0 + csw * 8], &Bs[row * 64]);
        }
        __syncthreads();
        short8 af0[4], af1[4], bf0[4], bf1[4];
#pragma unroll
        for (int t = 0; t < 4; t++) {
            int rowA = wy * 64 + t * 16 + l15;
            af0[t] = *(const short8*)&As[rowA * 64 + ((quad ^ sw) * 8)];
            af1[t] = *(const short8*)&As[rowA * 64 + (((quad + 4) ^ sw) * 8)];
            int rowB = wx * 64 + t * 16 + l15;
            bf0[t] = *(const short8*)&Bs[rowB * 64 + ((quad ^ sw) * 8)];
            bf1[t] = *(const short8*)&Bs[rowB * 64 + (((quad + 4) ^ sw) * 8)];
        }
#pragma unroll
        for (int mi = 0; mi < 4; mi++)
#pragma unroll
            for (int ni = 0; ni < 4; ni++) {
                acc[mi][ni] = mfma16(af0[mi], bf0[ni], acc[mi][ni]);
                acc[mi][ni] = mfma16(af1[mi], bf1[ni], acc[mi][ni]);
            }
        __syncthreads();
    }

#pragma unroll
    for (int mi = 0; mi < 4; mi++)
#pragma unroll
        for (int ni = 0; ni < 4; ni++)
#pragma unroll
            for (int r = 0; r < 4; r++) {
                int i = m0 + wy * 64 + mi * 16 + quad * 4 + r;
                int j = n0 + wx * 64 + ni * 16 + l15;
                out[(size_t)i * 512 + j] = acc[mi][ni][r];
            }
}

extern "C" void kernel_launch(void* const* d_in, const int* in_sizes, int n_in,
                              void* d_out, int out_size, void* d_ws, size_t ws_size,
                              hipStream_t stream) {
    const float* x     = (const float*)d_in[0];   // [2,4096,512]
    const float* w_qkv = (const float*)d_in[1];   // [1536,512]
    const float* w_o   = (const float*)d_in[2];   // [512,512]
    float* out = (float*)d_out;

    const size_t N_X   = (size_t)Bq * Lq * Dq;        // 4194304
    const size_t N_WQ  = (size_t)3 * Dq * Dq;         // 786432
    const size_t N_WO  = (size_t)Dq * Dq;             // 262144
    const size_t N_QKV = (size_t)Bq * Hq * Lq * DKq;  // 4194304 each

    u16* xb  = (u16*)d_ws;       // castall in; dead after qkv -> Opart0
    u16* wqb = xb + N_X;         // dead after qkv -> denp
    u16* wob = wqb + N_WQ;
    u16* qb  = wob + N_WO;       // dead after attn -> final ctx
    u16* kb  = qb + N_QKV;
    u16* vt  = kb + N_QKV;
    u16* o1r = vt + N_QKV;       // Opart1 region (total ws still ~44 MB)

    _Float16* op0  = (_Float16*)xb;
    _Float16* op1  = (_Float16*)o1r;
    float*    denp = (float*)wqb;     // [2][16][4096] fp32 = 512 KB <= 1.5 MB
    u16*      ctxq = qb;              // final bf16 ctx reuses qb

    castall<<<dim3(5120), 256, 0, stream>>>(x, w_qkv, w_o, xb, wqb, wob);
    qkv_gemm<<<dim3(64, 12), 256, 0, stream>>>(xb, wqb, qb, kb, vt);
    attn_kern<<<dim3(1024), 256, 0, stream>>>(qb, kb, vt, op0, op1, denp);
    combine<<<dim3(4096), 256, 0, stream>>>(op0, op1, denp, ctxq);
    out_gemm<<<dim3(64, 4), 256, 0, stream>>>(ctxq, wob, out);
}